// Round 13
// baseline (123.869 us; speedup 1.0000x reference)
//
#include <hip/hip_runtime.h>
#include <hip/hip_bf16.h>
#include <math.h>

typedef _Float16 f16x8 __attribute__((ext_vector_type(8)));
typedef _Float16 f16x4 __attribute__((ext_vector_type(4)));
typedef _Float16 f16x2 __attribute__((ext_vector_type(2)));
typedef __fp16 fp16x2 __attribute__((ext_vector_type(2)));
typedef float f32x4 __attribute__((ext_vector_type(4)));

#define MFMA16(a, b, c) __builtin_amdgcn_mfma_f32_16x16x32_f16((a), (b), (c), 0, 0, 0)

typedef __attribute__((address_space(3))) char as3_char;
typedef __attribute__((address_space(1))) const char as1_char;
__device__ __forceinline__ void glds16(const void* g, void* l) {
  __builtin_amdgcn_global_load_lds((as1_char*)g, (as3_char*)l, 16, 0, 0);
}

union F16x8u { f16x8 v; f16x2 h[4]; };

__device__ __forceinline__ f16x2 pkrtz(float a, float b) {
  fp16x2 r = __builtin_amdgcn_cvt_pkrtz(a, b);
  return __builtin_bit_cast(f16x2, r);
}

// ---------------- kernel 0: W -> chunked, pre-swizzled f16 hi/lo staging ----
// Wstg: 12 sub-chunks (K=32) x 1536 segs x 16B. Seg s2 = p*768 + r*4 + gg
// holds WT_p[r][c0*32 + g*8 .. +8], g = gg ^ ((r>>1)&3) (bank-spread swizzle).
__global__ __launch_bounds__(256) void wprep_kernel(
    const float* __restrict__ Wq, const float* __restrict__ Wk, const float* __restrict__ Wv,
    _Float16* __restrict__ wstg) {
  int s = blockIdx.x * 256 + threadIdx.x;  // 0..18431
  int c0 = s / 1536, s2 = s % 1536;
  int p = s2 / 768, r = (s2 % 768) / 4, gg = s2 & 3;
  int g = gg ^ ((r >> 1) & 3);
  int sel = r >> 6, h = r & 63;
  const float* W = (sel == 0) ? Wq : (sel == 1) ? Wk : Wv;
  f16x8 o;
#pragma unroll
  for (int e = 0; e < 8; ++e) {
    float val = W[(c0 * 32 + g * 8 + e) * 64 + h];
    _Float16 hi = (_Float16)val;
    o[e] = p ? (_Float16)(val - (float)hi) : hi;
  }
  *(f16x8*)&wstg[(size_t)s * 8] = o;
}

// ---------------- kernel 1: QKV GEMM -> fragment images --------------------
// 1024 blocks x 256 thr (4 waves). M-tile 128; wave w owns rows
// row0+32w..row0+32w+31 (2 sets of 16), all 192 cols. 256-thr block => reg
// cap 512 (no spills). LDS = W dbuf 48KB => 2 blocks/CU co-resident.
// Outputs: qimg [512][256][2][72] f16 (hi/lo fragment rows);
//          kvimg [512][53760] f16 = kh[256][72] | kl[256][72] | vT[64][264].
__global__ __launch_bounds__(256) void qkv_gemm(
    const float* __restrict__ x,
    const _Float16* __restrict__ wstg,
    _Float16* __restrict__ qimg,
    _Float16* __restrict__ kvimg) {
  __shared__ __align__(16) char smem[49152];
  char* wbuf0 = smem;
  char* wbuf1 = smem + 24576;

  const int tid = threadIdx.x;
  const int wave = tid >> 6, lane = tid & 63;
  const int g = lane >> 4, l16 = lane & 15;
  const int row0 = blockIdx.x * 128;
  const int b = row0 >> 8;
  const int r0l = row0 & 255;               // 0 or 128
  const int rs0 = row0 + 32 * wave;         // set0 global row base
  _Float16* kvb = kvimg + (size_t)b * 53760;

  const float* xrow0 = x + (size_t)(rs0 + l16) * 384 + g * 8;
  const float* xrow1 = xrow0 + 16 * 384;

  f32x4 qa[2][4] = {}, ka[2][4] = {}, va[2][4] = {};
  float4 buf[3][2][2];  // [stage][set][half]

  // prologue: W(0) glds (6/wave) + x(0), x(1)
#pragma unroll
  for (int i = 0; i < 6; ++i) {
    int seg0 = wave * 384 + i * 64;
    glds16(wstg + (size_t)(seg0 + lane) * 8, wbuf0 + seg0 * 16);
  }
  __builtin_amdgcn_sched_barrier(0);
#pragma unroll
  for (int p = 0; p < 2; ++p) {
    buf[p][0][0] = *(const float4*)(xrow0 + p * 32);
    buf[p][0][1] = *(const float4*)(xrow0 + p * 32 + 4);
    buf[p][1][0] = *(const float4*)(xrow1 + p * 32);
    buf[p][1][1] = *(const float4*)(xrow1 + p * 32 + 4);
  }
  __builtin_amdgcn_sched_barrier(0);
  asm volatile("s_waitcnt vmcnt(4) lgkmcnt(0)" ::: "memory");
  __builtin_amdgcn_s_barrier();
  __builtin_amdgcn_sched_barrier(0);

#pragma unroll
  for (int c = 0; c < 12; ++c) {
    if (c < 11) {
      char* nb = ((c + 1) & 1) ? wbuf1 : wbuf0;
      const _Float16* src = wstg + (size_t)(c + 1) * 12288;
#pragma unroll
      for (int i = 0; i < 6; ++i) {
        int seg0 = wave * 384 + i * 64;
        glds16(src + (size_t)(seg0 + lane) * 8, nb + seg0 * 16);
      }
    }
    __builtin_amdgcn_sched_barrier(0);
    if (c < 10) {
      buf[(c + 2) % 3][0][0] = *(const float4*)(xrow0 + (c + 2) * 32);
      buf[(c + 2) % 3][0][1] = *(const float4*)(xrow0 + (c + 2) * 32 + 4);
      buf[(c + 2) % 3][1][0] = *(const float4*)(xrow1 + (c + 2) * 32);
      buf[(c + 2) % 3][1][1] = *(const float4*)(xrow1 + (c + 2) * 32 + 4);
    }
    __builtin_amdgcn_sched_barrier(0);

    const char* wb = (c & 1) ? wbuf1 : wbuf0;
    f16x8 ah[2], al[2];
#pragma unroll
    for (int s = 0; s < 2; ++s) {
      float vv[8] = {buf[c % 3][s][0].x, buf[c % 3][s][0].y, buf[c % 3][s][0].z,
                     buf[c % 3][s][0].w, buf[c % 3][s][1].x, buf[c % 3][s][1].y,
                     buf[c % 3][s][1].z, buf[c % 3][s][1].w};
      F16x8u uh, ul;
#pragma unroll
      for (int k2 = 0; k2 < 4; ++k2) {
        float a = vv[2 * k2], bb = vv[2 * k2 + 1];
        f16x2 hp = pkrtz(a, bb);
        uh.h[k2] = hp;
        ul.h[k2] = pkrtz(a - (float)hp[0], bb - (float)hp[1]);
      }
      ah[s] = uh.v;
      al[s] = ul.v;
    }
#pragma unroll
    for (int ct = 0; ct < 4; ++ct) {
      const int rq = ct * 16 + l16;
      const int rk = 64 + rq;
      const int rv = 128 + rq;
      f16x8 bqh = *(const f16x8*)(wb + (0 * 768 + rq * 4 + (g ^ ((rq >> 1) & 3))) * 16);
      f16x8 bql = *(const f16x8*)(wb + (1 * 768 + rq * 4 + (g ^ ((rq >> 1) & 3))) * 16);
      f16x8 bkh = *(const f16x8*)(wb + (0 * 768 + rk * 4 + (g ^ ((rk >> 1) & 3))) * 16);
      f16x8 bkl = *(const f16x8*)(wb + (1 * 768 + rk * 4 + (g ^ ((rk >> 1) & 3))) * 16);
      f16x8 bvh = *(const f16x8*)(wb + (0 * 768 + rv * 4 + (g ^ ((rv >> 1) & 3))) * 16);
      __builtin_amdgcn_s_setprio(1);
#pragma unroll
      for (int s = 0; s < 2; ++s) {
        qa[s][ct] = MFMA16(ah[s], bqh, qa[s][ct]);
        qa[s][ct] = MFMA16(al[s], bqh, qa[s][ct]);
        qa[s][ct] = MFMA16(ah[s], bql, qa[s][ct]);
        ka[s][ct] = MFMA16(ah[s], bkh, ka[s][ct]);
        ka[s][ct] = MFMA16(al[s], bkh, ka[s][ct]);
        ka[s][ct] = MFMA16(ah[s], bkl, ka[s][ct]);
        va[s][ct] = MFMA16(ah[s], bvh, va[s][ct]);  // v: single pass
      }
      __builtin_amdgcn_s_setprio(0);
    }
    if (c < 10) {
      asm volatile("s_waitcnt vmcnt(4) lgkmcnt(0)" ::: "memory");
    } else if (c == 10) {
      asm volatile("s_waitcnt vmcnt(0) lgkmcnt(0)" ::: "memory");
    } else {
      asm volatile("s_waitcnt lgkmcnt(0)" ::: "memory");
    }
    __builtin_amdgcn_s_barrier();
    __builtin_amdgcn_sched_barrier(0);
  }

  // ---- epilogue: q frags + kh/kl to global; vT via LDS transpose ----
  _Float16* vls = (_Float16*)smem;  // [64][136] f16 (17408 B), W dead
#pragma unroll
  for (int s = 0; s < 2; ++s) {
#pragma unroll
    for (int ct = 0; ct < 4; ++ct) {
      const int h = ct * 16 + l16;
#pragma unroll
      for (int j = 0; j < 4; ++j) {
        const int rloc = r0l + 32 * wave + 16 * s + 4 * g + j;  // 0..255 in batch
        const int rl128 = 32 * wave + 16 * s + 4 * g + j;       // 0..127 in block
        float kv = ka[s][ct][j];
        _Float16 khv = (_Float16)kv;
        kvb[rloc * 72 + h] = khv;
        kvb[18432 + rloc * 72 + h] = (_Float16)(kv - (float)khv);
        float qv = qa[s][ct][j];
        _Float16 qh = (_Float16)qv;
        qimg[(((size_t)b * 256 + rloc) * 2 + 0) * 72 + h] = qh;
        qimg[(((size_t)b * 256 + rloc) * 2 + 1) * 72 + h] = (_Float16)(qv - (float)qh);
        vls[h * 136 + rl128] = (_Float16)va[s][ct][j];
      }
    }
  }
  __syncthreads();
  // coalesced vT copy-out: thread t -> h = t>>2, 32-col segment sg = t&3
  {
    const int h = tid >> 2, sg = tid & 3;
    const _Float16* src = vls + h * 136 + sg * 32;
    _Float16* dst = kvb + 36864 + h * 264 + r0l + sg * 32;
#pragma unroll
    for (int u = 0; u < 4; ++u)
      *(f16x8*)(dst + u * 8) = *(const f16x8*)(src + u * 8);
  }
}

// ---------------- kernel 2: causal flash attention -------------------------
// 512 blocks x 1024 thr (16 waves). Wave w owns q-rows 16w..16w+15.
// kv image glds-copied linearly into LDS (layout-identical); q frags direct
// from global. Per-SIMD balanced causal skip; no barriers after staging.
__global__ __launch_bounds__(1024) void attn_kernel(
    const _Float16* __restrict__ qimg,
    const _Float16* __restrict__ kvimg,
    float* __restrict__ out) {
  __shared__ __align__(16) char smem[144384];
  _Float16* kh = (_Float16*)smem;              // [256][72]
  _Float16* kl = (_Float16*)(smem + 36864);    // [256][72]
  _Float16* vT = (_Float16*)(smem + 73728);    // [64][264]
  _Float16* slc = (_Float16*)(smem + 107520);  // 16 x [16][72]

  const int tid = threadIdx.x;
  const int wave = tid >> 6, lane = tid & 63;
  const int g = lane >> 4, l16 = lane & 15;
  const int b = blockIdx.x;
  const int rs = 16 * wave;
  const int qr = rs + l16;

  const float K2 = 28.270933f;  // sqrt(384) * log2(e)
  const float NINF = -__builtin_inff();

  // ---- stage kv image: 6720 x 16B segs; waves 0..14 do 7 each ----
  const _Float16* kvb = kvimg + (size_t)b * 53760;
  if (wave < 15) {
#pragma unroll
    for (int i = 0; i < 7; ++i) {
      int idx = wave * 448 + i * 64 + lane;
      glds16(kvb + (size_t)idx * 8, smem + idx * 16);
    }
  }
  __builtin_amdgcn_sched_barrier(0);
  // q fragments direct from global (overlaps with glds)
  f16x8 qhf[2], qlf[2];
#pragma unroll
  for (int ks = 0; ks < 2; ++ks) {
    size_t o = (((size_t)b * 256 + qr) * 2) * 72 + ks * 32 + g * 8;
    qhf[ks] = *(const f16x8*)&qimg[o];
    qlf[ks] = *(const f16x8*)&qimg[o + 72];
  }
  asm volatile("s_waitcnt vmcnt(0) lgkmcnt(0)" ::: "memory");
  __builtin_amdgcn_s_barrier();
  __builtin_amdgcn_sched_barrier(0);

  // ---- causal flash attention (no barriers) ----
  _Float16* psl = slc + wave * 1152;  // per-wave P slice [16][72]
  float mrun = NINF, srun = 0.f;
  f32x4 O[4] = {};

  for (int c = 0; c < 4; ++c) {
    const int kb = c * 64;
    if (kb > rs + 15) continue;  // wave-uniform
    f32x4 sa[4] = {};
#pragma unroll
    for (int kt = 0; kt < 4; ++kt) {
      const int kr = kb + 16 * kt;
      if (kr > rs + 15) continue;  // wave-uniform
#pragma unroll
      for (int ks = 0; ks < 2; ++ks) {
        const int ko = (kr + l16) * 72 + ks * 32 + g * 8;
        f16x8 akh = *(const f16x8*)&kh[ko];
        f16x8 akl = *(const f16x8*)&kl[ko];
        __builtin_amdgcn_s_setprio(1);
        sa[kt] = MFMA16(akh, qhf[ks], sa[kt]);
        sa[kt] = MFMA16(akl, qhf[ks], sa[kt]);
        sa[kt] = MFMA16(akh, qlf[ks], sa[kt]);
        __builtin_amdgcn_s_setprio(0);
      }
    }
    float cm = NINF;
#pragma unroll
    for (int kt = 0; kt < 4; ++kt)
#pragma unroll
      for (int j = 0; j < 4; ++j) {
        const int krow = kb + 16 * kt + 4 * g + j;
        float sv = (krow <= qr) ? sa[kt][j] : NINF;
        sa[kt][j] = sv;
        cm = fmaxf(cm, sv);
      }
    cm = fmaxf(cm, __shfl_xor(cm, 16));
    cm = fmaxf(cm, __shfl_xor(cm, 32));
    const float mn = fmaxf(mrun, cm);
    const float scl = exp2f(K2 * (mrun - mn));
    mrun = mn;
    float cs = 0.f;
#pragma unroll
    for (int kt = 0; kt < 4; ++kt) {
      float p0 = exp2f(K2 * (sa[kt][0] - mn));
      float p1 = exp2f(K2 * (sa[kt][1] - mn));
      float p2 = exp2f(K2 * (sa[kt][2] - mn));
      float p3 = exp2f(K2 * (sa[kt][3] - mn));
      cs += (p0 + p1) + (p2 + p3);
      f16x2 lo2 = pkrtz(p0, p1), hi2 = pkrtz(p2, p3);
      f16x4 pk = {lo2[0], lo2[1], hi2[0], hi2[1]};
      *(f16x4*)&psl[l16 * 72 + kt * 16 + 4 * g] = pk;
    }
    cs += __shfl_xor(cs, 16);
    cs += __shfl_xor(cs, 32);
    srun = srun * scl + cs;
#pragma unroll
    for (int ht = 0; ht < 4; ++ht) O[ht] *= scl;
    asm volatile("s_waitcnt lgkmcnt(0)" ::: "memory");
    __builtin_amdgcn_sched_barrier(0);
#pragma unroll
    for (int ks2 = 0; ks2 < 2; ++ks2) {
      f16x8 bp = *(const f16x8*)&psl[l16 * 72 + ks2 * 32 + g * 8];
#pragma unroll
      for (int ht = 0; ht < 4; ++ht) {
        f16x8 av = *(const f16x8*)&vT[(ht * 16 + l16) * 264 + kb + ks2 * 32 + g * 8];
        __builtin_amdgcn_s_setprio(1);
        O[ht] = MFMA16(av, bp, O[ht]);
        __builtin_amdgcn_s_setprio(0);
      }
    }
  }

  const float inv = 1.0f / srun;
#pragma unroll
  for (int ht = 0; ht < 4; ++ht) {
    f32x4 r = O[ht] * inv;
    *(f32x4*)&out[((size_t)b * 256 + qr) * 64 + ht * 16 + 4 * g] = r;
  }
}

// ---------------------------------------------------------------------------
extern "C" void kernel_launch(void* const* d_in, const int* in_sizes, int n_in,
                              void* d_out, int out_size, void* d_ws, size_t ws_size,
                              hipStream_t stream) {
  const float* x  = (const float*)d_in[0];
  const float* Wq = (const float*)d_in[1];
  const float* Wk = (const float*)d_in[2];
  const float* Wv = (const float*)d_in[3];

  char* ws = (char*)d_ws;
  _Float16* wstg  = (_Float16*)ws;                     // 294912 B
  _Float16* qimg  = (_Float16*)(ws + (1 << 20));       // 512*256*2*72 f16 = 37748736 B
  _Float16* kvimg = (_Float16*)(ws + (1 << 20) + 37748736);  // 512*53760 f16 = 55050240 B

  wprep_kernel<<<72, 256, 0, stream>>>(Wq, Wk, Wv, wstg);
  qkv_gemm<<<1024, 256, 0, stream>>>(x, wstg, qimg, kvimg);
  attn_kernel<<<512, 1024, 0, stream>>>(qimg, kvimg, (float*)d_out);
}

// Round 14
// 116.977 us; speedup vs baseline: 1.0589x; 1.0589x over previous
//
#include <hip/hip_runtime.h>
#include <hip/hip_bf16.h>
#include <math.h>

typedef _Float16 f16x8 __attribute__((ext_vector_type(8)));
typedef _Float16 f16x4 __attribute__((ext_vector_type(4)));
typedef _Float16 f16x2 __attribute__((ext_vector_type(2)));
typedef __fp16 fp16x2 __attribute__((ext_vector_type(2)));
typedef float f32x4 __attribute__((ext_vector_type(4)));

#define MFMA16(a, b, c) __builtin_amdgcn_mfma_f32_16x16x32_f16((a), (b), (c), 0, 0, 0)

typedef __attribute__((address_space(3))) char as3_char;
typedef __attribute__((address_space(1))) const char as1_char;
__device__ __forceinline__ void glds16(const void* g, void* l) {
  __builtin_amdgcn_global_load_lds((as1_char*)g, (as3_char*)l, 16, 0, 0);
}

union F16x8u { f16x8 v; f16x2 h[4]; };

__device__ __forceinline__ f16x2 pkrtz(float a, float b) {
  fp16x2 r = __builtin_amdgcn_cvt_pkrtz(a, b);
  return __builtin_bit_cast(f16x2, r);
}

// ---------------- kernel 0: W -> chunked, pre-swizzled f16 hi/lo staging ----
// Wstg: 12 sub-chunks (K=32) x 1536 segs x 16B. Seg s2 = p*768 + r*4 + gg
// holds WT_p[r][c0*32 + g*8 .. +8], g = gg ^ ((r>>1)&3) (bank-spread swizzle).
__global__ __launch_bounds__(256) void wprep_kernel(
    const float* __restrict__ Wq, const float* __restrict__ Wk, const float* __restrict__ Wv,
    _Float16* __restrict__ wstg) {
  int s = blockIdx.x * 256 + threadIdx.x;  // 0..18431
  int c0 = s / 1536, s2 = s % 1536;
  int p = s2 / 768, r = (s2 % 768) / 4, gg = s2 & 3;
  int g = gg ^ ((r >> 1) & 3);
  int sel = r >> 6, h = r & 63;
  const float* W = (sel == 0) ? Wq : (sel == 1) ? Wk : Wv;
  f16x8 o;
#pragma unroll
  for (int e = 0; e < 8; ++e) {
    float val = W[(c0 * 32 + g * 8 + e) * 64 + h];
    _Float16 hi = (_Float16)val;
    o[e] = p ? (_Float16)(val - (float)hi) : hi;
  }
  *(f16x8*)&wstg[(size_t)s * 8] = o;
}

// ---------------- kernel 1: QKV GEMM -> fragment images --------------------
// 512 blocks x 512 thr (8 waves). Block = one batch (256 rows). Wave w owns
// rows 32w..32w+31 (2 sets of 16) x all 192 cols: B-frags read once per 2
// M-tiles. K=64 chunks (6 iters), W LDS-dbuf 2x48KB via glds 1-ahead; x raw
// 1-ahead in regs, converted at chunk start. ~186 live regs, 512-thr block
// => 256-reg cap => spill-free by construction.
__global__ __launch_bounds__(512) void qkv_gemm(
    const float* __restrict__ x,
    const _Float16* __restrict__ wstg,
    _Float16* __restrict__ qimg,
    _Float16* __restrict__ kvimg) {
  __shared__ __align__(16) char smem[98304];
  char* wbuf0 = smem;                // 49152 B
  char* wbuf1 = smem + 49152;        // 49152 B
  _Float16* vls = (_Float16*)smem;   // [64][272] f16 (34816 B) ALIAS, epilogue

  const int tid = threadIdx.x;
  const int wave = tid >> 6, lane = tid & 63;
  const int g = lane >> 4, l16 = lane & 15;
  const int b = blockIdx.x;
  const int rs0 = 32 * wave;
  _Float16* kvb = kvimg + (size_t)b * 53760;

  const float* xrow0 = x + ((size_t)b * 256 + rs0 + l16) * 384 + g * 8;
  const float* xrow1 = xrow0 + 16 * 384;

  f32x4 qa[2][4] = {}, ka[2][4] = {}, va[2][4] = {};
  float4 raw[2][2][2];   // [set][khalf][half8] raw x of next chunk
  f16x8 ah[2][2], al[2][2];  // [set][khalf] converted current chunk

  // prologue: W(0) glds (6/wave) + x(0) raw
#pragma unroll
  for (int i = 0; i < 6; ++i) {
    int seg0 = wave * 384 + i * 64;
    glds16(wstg + (size_t)(seg0 + lane) * 8, wbuf0 + seg0 * 16);
  }
  __builtin_amdgcn_sched_barrier(0);
#pragma unroll
  for (int s = 0; s < 2; ++s) {
    const float* xr = s ? xrow1 : xrow0;
#pragma unroll
    for (int ks = 0; ks < 2; ++ks) {
      raw[s][ks][0] = *(const float4*)(xr + ks * 32);
      raw[s][ks][1] = *(const float4*)(xr + ks * 32 + 4);
    }
  }
  __builtin_amdgcn_sched_barrier(0);
  asm volatile("s_waitcnt vmcnt(0) lgkmcnt(0)" ::: "memory");
  __builtin_amdgcn_s_barrier();
  __builtin_amdgcn_sched_barrier(0);

#pragma unroll
  for (int c = 0; c < 6; ++c) {
    // convert raw x(c) -> ah/al (frees raw for c+1)
#pragma unroll
    for (int s = 0; s < 2; ++s)
#pragma unroll
      for (int ks = 0; ks < 2; ++ks) {
        float vv[8] = {raw[s][ks][0].x, raw[s][ks][0].y, raw[s][ks][0].z,
                       raw[s][ks][0].w, raw[s][ks][1].x, raw[s][ks][1].y,
                       raw[s][ks][1].z, raw[s][ks][1].w};
        F16x8u uh, ul;
#pragma unroll
        for (int k2 = 0; k2 < 4; ++k2) {
          float a = vv[2 * k2], bb = vv[2 * k2 + 1];
          f16x2 hp = pkrtz(a, bb);
          uh.h[k2] = hp;
          ul.h[k2] = pkrtz(a - (float)hp[0], bb - (float)hp[1]);
        }
        ah[s][ks] = uh.v;
        al[s][ks] = ul.v;
      }
    __builtin_amdgcn_sched_barrier(0);
    // issue W(c+1) glds + x(c+1) raw (drained only at end of this chunk)
    if (c < 5) {
      char* nb = ((c + 1) & 1) ? wbuf1 : wbuf0;
      const _Float16* src = wstg + (size_t)(c + 1) * 24576;
#pragma unroll
      for (int i = 0; i < 6; ++i) {
        int seg0 = wave * 384 + i * 64;
        glds16(src + (size_t)(seg0 + lane) * 8, nb + seg0 * 16);
      }
#pragma unroll
      for (int s = 0; s < 2; ++s) {
        const float* xr = s ? xrow1 : xrow0;
#pragma unroll
        for (int ks = 0; ks < 2; ++ks) {
          raw[s][ks][0] = *(const float4*)(xr + (c + 1) * 64 + ks * 32);
          raw[s][ks][1] = *(const float4*)(xr + (c + 1) * 64 + ks * 32 + 4);
        }
      }
    }
    __builtin_amdgcn_sched_barrier(0);

    // compute chunk c: 40 ds_read_b128 feed 112 MFMA per wave
    const char* wb = (c & 1) ? wbuf1 : wbuf0;
#pragma unroll
    for (int ks = 0; ks < 2; ++ks) {
      const char* wbk = wb + ks * 24576;
#pragma unroll
      for (int ct = 0; ct < 4; ++ct) {
        const int rq = ct * 16 + l16;
        const int rk = 64 + rq;
        const int rv = 128 + rq;
        f16x8 bqh = *(const f16x8*)(wbk + (0 * 768 + rq * 4 + (g ^ ((rq >> 1) & 3))) * 16);
        f16x8 bql = *(const f16x8*)(wbk + (1 * 768 + rq * 4 + (g ^ ((rq >> 1) & 3))) * 16);
        f16x8 bkh = *(const f16x8*)(wbk + (0 * 768 + rk * 4 + (g ^ ((rk >> 1) & 3))) * 16);
        f16x8 bkl = *(const f16x8*)(wbk + (1 * 768 + rk * 4 + (g ^ ((rk >> 1) & 3))) * 16);
        f16x8 bvh = *(const f16x8*)(wbk + (0 * 768 + rv * 4 + (g ^ ((rv >> 1) & 3))) * 16);
        __builtin_amdgcn_s_setprio(1);
#pragma unroll
        for (int s = 0; s < 2; ++s) {
          qa[s][ct] = MFMA16(ah[s][ks], bqh, qa[s][ct]);
          qa[s][ct] = MFMA16(al[s][ks], bqh, qa[s][ct]);
          qa[s][ct] = MFMA16(ah[s][ks], bql, qa[s][ct]);
          ka[s][ct] = MFMA16(ah[s][ks], bkh, ka[s][ct]);
          ka[s][ct] = MFMA16(al[s][ks], bkh, ka[s][ct]);
          ka[s][ct] = MFMA16(ah[s][ks], bkl, ka[s][ct]);
          va[s][ct] = MFMA16(ah[s][ks], bvh, va[s][ct]);  // v: single pass
        }
        __builtin_amdgcn_s_setprio(0);
      }
    }
    // drain W(c+1)+x(c+1) (issued before ~2500-cy compute -> cheap) and sync
    if (c < 5) {
      asm volatile("s_waitcnt vmcnt(0) lgkmcnt(0)" ::: "memory");
    } else {
      asm volatile("s_waitcnt lgkmcnt(0)" ::: "memory");
    }
    __builtin_amdgcn_s_barrier();
    __builtin_amdgcn_sched_barrier(0);
  }

  // ---- epilogue: q frags + kh/kl to global; vT via aliased LDS transpose --
#pragma unroll
  for (int s = 0; s < 2; ++s) {
#pragma unroll
    for (int ct = 0; ct < 4; ++ct) {
      const int h = ct * 16 + l16;
#pragma unroll
      for (int j = 0; j < 4; ++j) {
        const int rloc = rs0 + 16 * s + 4 * g + j;  // 0..255
        float kv = ka[s][ct][j];
        _Float16 khv = (_Float16)kv;
        kvb[rloc * 72 + h] = khv;
        kvb[18432 + rloc * 72 + h] = (_Float16)(kv - (float)khv);
        float qv = qa[s][ct][j];
        _Float16 qh = (_Float16)qv;
        qimg[(((size_t)b * 256 + rloc) * 2 + 0) * 72 + h] = qh;
        qimg[(((size_t)b * 256 + rloc) * 2 + 1) * 72 + h] = (_Float16)(qv - (float)qh);
        vls[h * 272 + rloc] = (_Float16)va[s][ct][j];
      }
    }
  }
  __syncthreads();
  // coalesced vT copy-out: thread t -> h = t>>3, 32-col segment sg = t&7
  {
    const int h = tid >> 3, sg = tid & 7;
    const _Float16* src = vls + h * 272 + sg * 32;
    _Float16* dst = kvb + 36864 + h * 264 + sg * 32;
#pragma unroll
    for (int u = 0; u < 4; ++u)
      *(f16x8*)(dst + u * 8) = *(const f16x8*)(src + u * 8);
  }
}

// ---------------- kernel 2: causal flash attention -------------------------
// 512 blocks x 1024 thr (16 waves). Wave w owns q-rows 16w..16w+15.
// kv image glds-copied linearly into LDS (layout-identical); q frags direct
// from global. Per-SIMD balanced causal skip; no barriers after staging.
__global__ __launch_bounds__(1024) void attn_kernel(
    const _Float16* __restrict__ qimg,
    const _Float16* __restrict__ kvimg,
    float* __restrict__ out) {
  __shared__ __align__(16) char smem[144384];
  _Float16* kh = (_Float16*)smem;              // [256][72]
  _Float16* kl = (_Float16*)(smem + 36864);    // [256][72]
  _Float16* vT = (_Float16*)(smem + 73728);    // [64][264]
  _Float16* slc = (_Float16*)(smem + 107520);  // 16 x [16][72]

  const int tid = threadIdx.x;
  const int wave = tid >> 6, lane = tid & 63;
  const int g = lane >> 4, l16 = lane & 15;
  const int b = blockIdx.x;
  const int rs = 16 * wave;
  const int qr = rs + l16;

  const float K2 = 28.270933f;  // sqrt(384) * log2(e)
  const float NINF = -__builtin_inff();

  // ---- stage kv image: 6720 x 16B segs; waves 0..14 do 7 each ----
  const _Float16* kvb = kvimg + (size_t)b * 53760;
  if (wave < 15) {
#pragma unroll
    for (int i = 0; i < 7; ++i) {
      int idx = wave * 448 + i * 64 + lane;
      glds16(kvb + (size_t)idx * 8, smem + idx * 16);
    }
  }
  __builtin_amdgcn_sched_barrier(0);
  // q fragments direct from global (overlaps with glds)
  f16x8 qhf[2], qlf[2];
#pragma unroll
  for (int ks = 0; ks < 2; ++ks) {
    size_t o = (((size_t)b * 256 + qr) * 2) * 72 + ks * 32 + g * 8;
    qhf[ks] = *(const f16x8*)&qimg[o];
    qlf[ks] = *(const f16x8*)&qimg[o + 72];
  }
  asm volatile("s_waitcnt vmcnt(0) lgkmcnt(0)" ::: "memory");
  __builtin_amdgcn_s_barrier();
  __builtin_amdgcn_sched_barrier(0);

  // ---- causal flash attention (no barriers) ----
  _Float16* psl = slc + wave * 1152;  // per-wave P slice [16][72]
  float mrun = NINF, srun = 0.f;
  f32x4 O[4] = {};

  for (int c = 0; c < 4; ++c) {
    const int kb = c * 64;
    if (kb > rs + 15) continue;  // wave-uniform
    f32x4 sa[4] = {};
#pragma unroll
    for (int kt = 0; kt < 4; ++kt) {
      const int kr = kb + 16 * kt;
      if (kr > rs + 15) continue;  // wave-uniform
#pragma unroll
      for (int ks = 0; ks < 2; ++ks) {
        const int ko = (kr + l16) * 72 + ks * 32 + g * 8;
        f16x8 akh = *(const f16x8*)&kh[ko];
        f16x8 akl = *(const f16x8*)&kl[ko];
        __builtin_amdgcn_s_setprio(1);
        sa[kt] = MFMA16(akh, qhf[ks], sa[kt]);
        sa[kt] = MFMA16(akl, qhf[ks], sa[kt]);
        sa[kt] = MFMA16(akh, qlf[ks], sa[kt]);
        __builtin_amdgcn_s_setprio(0);
      }
    }
    float cm = NINF;
#pragma unroll
    for (int kt = 0; kt < 4; ++kt)
#pragma unroll
      for (int j = 0; j < 4; ++j) {
        const int krow = kb + 16 * kt + 4 * g + j;
        float sv = (krow <= qr) ? sa[kt][j] : NINF;
        sa[kt][j] = sv;
        cm = fmaxf(cm, sv);
      }
    cm = fmaxf(cm, __shfl_xor(cm, 16));
    cm = fmaxf(cm, __shfl_xor(cm, 32));
    const float mn = fmaxf(mrun, cm);
    const float scl = exp2f(K2 * (mrun - mn));
    mrun = mn;
    float cs = 0.f;
#pragma unroll
    for (int kt = 0; kt < 4; ++kt) {
      float p0 = exp2f(K2 * (sa[kt][0] - mn));
      float p1 = exp2f(K2 * (sa[kt][1] - mn));
      float p2 = exp2f(K2 * (sa[kt][2] - mn));
      float p3 = exp2f(K2 * (sa[kt][3] - mn));
      cs += (p0 + p1) + (p2 + p3);
      f16x2 lo2 = pkrtz(p0, p1), hi2 = pkrtz(p2, p3);
      f16x4 pk = {lo2[0], lo2[1], hi2[0], hi2[1]};
      *(f16x4*)&psl[l16 * 72 + kt * 16 + 4 * g] = pk;
    }
    cs += __shfl_xor(cs, 16);
    cs += __shfl_xor(cs, 32);
    srun = srun * scl + cs;
#pragma unroll
    for (int ht = 0; ht < 4; ++ht) O[ht] *= scl;
    asm volatile("s_waitcnt lgkmcnt(0)" ::: "memory");
    __builtin_amdgcn_sched_barrier(0);
#pragma unroll
    for (int ks2 = 0; ks2 < 2; ++ks2) {
      f16x8 bp = *(const f16x8*)&psl[l16 * 72 + ks2 * 32 + g * 8];
#pragma unroll
      for (int ht = 0; ht < 4; ++ht) {
        f16x8 av = *(const f16x8*)&vT[(ht * 16 + l16) * 264 + kb + ks2 * 32 + g * 8];
        __builtin_amdgcn_s_setprio(1);
        O[ht] = MFMA16(av, bp, O[ht]);
        __builtin_amdgcn_s_setprio(0);
      }
    }
  }

  const float inv = 1.0f / srun;
#pragma unroll
  for (int ht = 0; ht < 4; ++ht) {
    f32x4 r = O[ht] * inv;
    *(f32x4*)&out[((size_t)b * 256 + qr) * 64 + ht * 16 + 4 * g] = r;
  }
}

// ---------------------------------------------------------------------------
extern "C" void kernel_launch(void* const* d_in, const int* in_sizes, int n_in,
                              void* d_out, int out_size, void* d_ws, size_t ws_size,
                              hipStream_t stream) {
  const float* x  = (const float*)d_in[0];
  const float* Wq = (const float*)d_in[1];
  const float* Wk = (const float*)d_in[2];
  const float* Wv = (const float*)d_in[3];

  char* ws = (char*)d_ws;
  _Float16* wstg  = (_Float16*)ws;                           // 294912 B
  _Float16* qimg  = (_Float16*)(ws + (1 << 20));             // 37748736 B
  _Float16* kvimg = (_Float16*)(ws + (1 << 20) + 37748736);  // 55050240 B

  wprep_kernel<<<72, 256, 0, stream>>>(Wq, Wk, Wv, wstg);
  qkv_gemm<<<512, 512, 0, stream>>>(x, wstg, qimg, kvimg);
  attn_kernel<<<512, 1024, 0, stream>>>(qimg, kvimg, (float*)d_out);
}

// Round 15
// 82.205 us; speedup vs baseline: 1.5068x; 1.4230x over previous
//
#include <hip/hip_runtime.h>
#include <hip/hip_bf16.h>
#include <math.h>

typedef _Float16 f16x8 __attribute__((ext_vector_type(8)));
typedef _Float16 f16x4 __attribute__((ext_vector_type(4)));
typedef _Float16 f16x2 __attribute__((ext_vector_type(2)));
typedef __fp16 fp16x2 __attribute__((ext_vector_type(2)));
typedef float f32x4 __attribute__((ext_vector_type(4)));

#define MFMA16(a, b, c) __builtin_amdgcn_mfma_f32_16x16x32_f16((a), (b), (c), 0, 0, 0)

typedef __attribute__((address_space(3))) char as3_char;
typedef __attribute__((address_space(1))) const char as1_char;
__device__ __forceinline__ void glds16(const void* g, void* l) {
  __builtin_amdgcn_global_load_lds((as1_char*)g, (as3_char*)l, 16, 0, 0);
}

union F16x8u { f16x8 v; f16x2 h[4]; };

__device__ __forceinline__ f16x2 pkrtz(float a, float b) {
  fp16x2 r = __builtin_amdgcn_cvt_pkrtz(a, b);
  return __builtin_bit_cast(f16x2, r);
}

// ---------------- kernel 0: W -> chunked, pre-swizzled f16 hi/lo staging ----
// Wstg: 12 chunks x 1536 segs x 16B. Seg s2 = p*768 + r*4 + gg holds
// WT_p[r][c0*32 + g*8 .. +8] where g = gg ^ ((r>>1)&3)  (bank-spread swizzle).
__global__ __launch_bounds__(256) void wprep_kernel(
    const float* __restrict__ Wq, const float* __restrict__ Wk, const float* __restrict__ Wv,
    _Float16* __restrict__ wstg) {
  int s = blockIdx.x * 256 + threadIdx.x;  // 0..18431
  int c0 = s / 1536, s2 = s % 1536;
  int p = s2 / 768, r = (s2 % 768) / 4, gg = s2 & 3;
  int g = gg ^ ((r >> 1) & 3);
  int sel = r >> 6, h = r & 63;
  const float* W = (sel == 0) ? Wq : (sel == 1) ? Wk : Wv;
  f16x8 o;
#pragma unroll
  for (int e = 0; e < 8; ++e) {
    float val = W[(c0 * 32 + g * 8 + e) * 64 + h];
    _Float16 hi = (_Float16)val;
    o[e] = p ? (_Float16)(val - (float)hi) : hi;
  }
  *(f16x8*)&wstg[(size_t)s * 8] = o;
}

// ---------------- fused kernel: one block per batch, 16 waves --------------
// Wave w owns q-rows 16w..16w+15. 4 waves/SIMD.
// Phase A: qkv proj, W LDS-dbuf via glds (counted vmcnt), x in regs 2-deep.
// Per-ct sched_barrier(0) caps live B-frags at 5 (20 VGPR) -> no spills
// under the 64-arch-VGPR cap a 1024-thr block forces.
// Phase B: causal flash attention, barrier-free, per-SIMD work balanced.
__global__ __launch_bounds__(1024) void fused_kernel(
    const float* __restrict__ x,
    const _Float16* __restrict__ wstg,
    float* __restrict__ out) {
  __shared__ __align__(16) char smem[156672];
  _Float16* kh = (_Float16*)smem;              // [256][72] f16 (36864 B)
  _Float16* kl = (_Float16*)(smem + 36864);    // [256][72] f16
  _Float16* vT = (_Float16*)(smem + 73728);    // [64][264] f16 (33792 B)
  char* wbuf0 = smem + 107520;                 // W chunk buf (24576 B)
  char* wbuf1 = smem + 132096;                 // W chunk buf (24576 B)
  _Float16* slc = (_Float16*)(smem + 107520);  // ALIAS (dead after phase A)

  const int tid = threadIdx.x;
  const int wave = tid >> 6, lane = tid & 63;
  const int g = lane >> 4, l16 = lane & 15;
  const int b = blockIdx.x;
  const int rs = 16 * wave;       // this wave's q-row set
  const int qr = rs + l16;        // this lane's q-row
  const float* xb = x + (size_t)b * 98304;  // 256*384

  const float K2 = 28.270933f;  // sqrt(384) * log2(e)
  const float NINF = -__builtin_inff();

  const float* xrow = xb + (size_t)qr * 384 + g * 8;  // 32B per chunk

  // ---------------- Phase A ----------------
  f32x4 qa[4] = {}, ka[4] = {}, va[4] = {};
  float4 buf[3][2];  // [stage][half], statically indexed (full unroll)

  // prologue: W(0) glds (waves 0-11), then x(0), x(1)
  if (wave < 12) {
#pragma unroll
    for (int i = 0; i < 2; ++i) {
      int seg0 = wave * 128 + i * 64;
      glds16(wstg + (size_t)(seg0 + lane) * 8, wbuf0 + seg0 * 16);
    }
  }
  __builtin_amdgcn_sched_barrier(0);
#pragma unroll
  for (int p = 0; p < 2; ++p) {
    buf[p][0] = *(const float4*)(xrow + p * 32);
    buf[p][1] = *(const float4*)(xrow + p * 32 + 4);
  }
  __builtin_amdgcn_sched_barrier(0);
  asm volatile("s_waitcnt vmcnt(2) lgkmcnt(0)" ::: "memory");
  __builtin_amdgcn_s_barrier();
  __builtin_amdgcn_sched_barrier(0);

#pragma unroll
  for (int c = 0; c < 12; ++c) {
    // issue glds for W(c+1) into the other buffer (waves 0-11)
    if (wave < 12 && c < 11) {
      char* nb = ((c + 1) & 1) ? wbuf1 : wbuf0;
      const _Float16* src = wstg + (size_t)(c + 1) * 12288;  // 1536*8 f16
#pragma unroll
      for (int i = 0; i < 2; ++i) {
        int seg0 = wave * 128 + i * 64;
        glds16(src + (size_t)(seg0 + lane) * 8, nb + seg0 * 16);
      }
    }
    __builtin_amdgcn_sched_barrier(0);
    // issue x prefetch for chunk c+2
    if (c < 10) {
      buf[(c + 2) % 3][0] = *(const float4*)(xrow + (c + 2) * 32);
      buf[(c + 2) % 3][1] = *(const float4*)(xrow + (c + 2) * 32 + 4);
    }
    __builtin_amdgcn_sched_barrier(0);

    // convert chunk c to f16 hi/lo A-fragments (packed cvt)
    const char* wb = (c & 1) ? wbuf1 : wbuf0;
    f16x8 ah, al;
    {
      float vv[8] = {buf[c % 3][0].x, buf[c % 3][0].y, buf[c % 3][0].z,
                     buf[c % 3][0].w, buf[c % 3][1].x, buf[c % 3][1].y,
                     buf[c % 3][1].z, buf[c % 3][1].w};
      F16x8u uh, ul;
#pragma unroll
      for (int k2 = 0; k2 < 4; ++k2) {
        float a = vv[2 * k2], bb = vv[2 * k2 + 1];
        f16x2 hp = pkrtz(a, bb);
        uh.h[k2] = hp;
        ul.h[k2] = pkrtz(a - (float)hp[0], bb - (float)hp[1]);
      }
      ah = uh.v;
      al = ul.v;
    }
    // compute: B-frags from LDS (swizzled), 28 MFMA per wave.
    // sched_barrier per ct: max 5 B-frags (20 VGPR) live -> no spills.
#pragma unroll
    for (int ct = 0; ct < 4; ++ct) {
      const int rq = ct * 16 + l16;        // q row (WT row)
      const int rk = 64 + rq;              // k row
      const int rv = 128 + rq;             // v row
      f16x8 bqh = *(const f16x8*)(wb + (0 * 768 + rq * 4 + (g ^ ((rq >> 1) & 3))) * 16);
      f16x8 bql = *(const f16x8*)(wb + (1 * 768 + rq * 4 + (g ^ ((rq >> 1) & 3))) * 16);
      f16x8 bkh = *(const f16x8*)(wb + (0 * 768 + rk * 4 + (g ^ ((rk >> 1) & 3))) * 16);
      f16x8 bkl = *(const f16x8*)(wb + (1 * 768 + rk * 4 + (g ^ ((rk >> 1) & 3))) * 16);
      f16x8 bvh = *(const f16x8*)(wb + (0 * 768 + rv * 4 + (g ^ ((rv >> 1) & 3))) * 16);
      __builtin_amdgcn_s_setprio(1);
      qa[ct] = MFMA16(ah, bqh, qa[ct]);
      qa[ct] = MFMA16(al, bqh, qa[ct]);
      qa[ct] = MFMA16(ah, bql, qa[ct]);
      ka[ct] = MFMA16(ah, bkh, ka[ct]);
      ka[ct] = MFMA16(al, bkh, ka[ct]);
      ka[ct] = MFMA16(ah, bkl, ka[ct]);
      va[ct] = MFMA16(ah, bvh, va[ct]);  // v: single pass
      __builtin_amdgcn_s_setprio(0);
      __builtin_amdgcn_sched_barrier(0);  // fence: cap live frag regs
    }
    // counted drain: x(c+1)+W(c+1) done, x(c+2) stays in flight (all waves)
    if (c < 10) {
      asm volatile("s_waitcnt vmcnt(2) lgkmcnt(0)" ::: "memory");
    } else if (c == 10) {
      asm volatile("s_waitcnt vmcnt(0) lgkmcnt(0)" ::: "memory");
    } else {
      asm volatile("s_waitcnt lgkmcnt(0)" ::: "memory");
    }
    __builtin_amdgcn_s_barrier();
    __builtin_amdgcn_sched_barrier(0);
  }

  // ---- epilogue: k hi/lo + vT to LDS (cross-wave data) ----
#pragma unroll
  for (int ct = 0; ct < 4; ++ct) {
    const int h = ct * 16 + l16;
#pragma unroll
    for (int j = 0; j < 4; ++j) {
      const int row = rs + 4 * g + j;
      float kv = ka[ct][j];
      _Float16 khv = (_Float16)kv;
      kh[row * 72 + h] = khv;
      kl[row * 72 + h] = (_Float16)(kv - (float)khv);
      vT[h * 264 + row] = (_Float16)va[ct][j];
    }
  }
  __syncthreads();  // (a) W-buf reads done everywhere; slc region free

  // ---- q redistribution via slc, two 8-wave rounds ----
  _Float16* myq = slc + (wave & 7) * 2304;  // [32][72] f16 slice
  f16x8 qhf[2], qlf[2];
#pragma unroll
  for (int rnd = 0; rnd < 2; ++rnd) {
    if ((wave >> 3) == rnd) {
#pragma unroll
      for (int ct = 0; ct < 4; ++ct) {
        const int h = ct * 16 + l16;
#pragma unroll
        for (int j = 0; j < 4; ++j) {
          const int rl = 4 * g + j;
          float qv = qa[ct][j];
          _Float16 qh = (_Float16)qv;
          myq[(rl * 2 + 0) * 72 + h] = qh;
          myq[(rl * 2 + 1) * 72 + h] = (_Float16)(qv - (float)qh);
        }
      }
    }
    __syncthreads();
    if ((wave >> 3) == rnd) {
#pragma unroll
      for (int ks = 0; ks < 2; ++ks) {
        qhf[ks] = *(const f16x8*)&myq[(l16 * 2 + 0) * 72 + ks * 32 + g * 8];
        qlf[ks] = *(const f16x8*)&myq[(l16 * 2 + 1) * 72 + ks * 32 + g * 8];
      }
    }
    __syncthreads();
  }
  asm volatile("s_waitcnt lgkmcnt(0)" ::: "memory");
  __builtin_amdgcn_sched_barrier(0);

  // ---------------- Phase B: causal flash attention (no barriers) ----------
  // Per-SIMD balanced: SIMD s hosts waves {s,s+4,s+8,s+12} = 1+2+3+4 chunks.
  _Float16* psl = slc + wave * 1152;  // per-wave private P slice [16][72]
  float mrun = NINF, srun = 0.f;
  f32x4 O[4] = {};

  for (int c = 0; c < 4; ++c) {
    const int kb = c * 64;
    if (kb > rs + 15) continue;  // wave-uniform
    // QK^T swapped: sa[kt][j] = S[qr][kb+16kt+4g+j]
    f32x4 sa[4] = {};
#pragma unroll
    for (int kt = 0; kt < 4; ++kt) {
      const int kr = kb + 16 * kt;
      if (kr > rs + 15) continue;  // fully-masked tile (wave-uniform)
#pragma unroll
      for (int ks = 0; ks < 2; ++ks) {
        const int ko = (kr + l16) * 72 + ks * 32 + g * 8;
        f16x8 akh = *(const f16x8*)&kh[ko];
        f16x8 akl = *(const f16x8*)&kl[ko];
        __builtin_amdgcn_s_setprio(1);
        sa[kt] = MFMA16(akh, qhf[ks], sa[kt]);
        sa[kt] = MFMA16(akl, qhf[ks], sa[kt]);
        sa[kt] = MFMA16(akh, qlf[ks], sa[kt]);
        __builtin_amdgcn_s_setprio(0);
      }
    }
    // causal mask + chunk max
    float cm = NINF;
#pragma unroll
    for (int kt = 0; kt < 4; ++kt)
#pragma unroll
      for (int j = 0; j < 4; ++j) {
        const int krow = kb + 16 * kt + 4 * g + j;
        float sv = (krow <= qr) ? sa[kt][j] : NINF;
        sa[kt][j] = sv;
        cm = fmaxf(cm, sv);
      }
    cm = fmaxf(cm, __shfl_xor(cm, 16));
    cm = fmaxf(cm, __shfl_xor(cm, 32));
    const float mn = fmaxf(mrun, cm);
    const float scl = exp2f(K2 * (mrun - mn));  // 0 on first chunk
    mrun = mn;
    // P = exp2(K2*(S-m)) -> packed f16x4 writes; sum
    float cs = 0.f;
#pragma unroll
    for (int kt = 0; kt < 4; ++kt) {
      float p0 = exp2f(K2 * (sa[kt][0] - mn));
      float p1 = exp2f(K2 * (sa[kt][1] - mn));
      float p2 = exp2f(K2 * (sa[kt][2] - mn));
      float p3 = exp2f(K2 * (sa[kt][3] - mn));
      cs += (p0 + p1) + (p2 + p3);
      f16x2 lo2 = pkrtz(p0, p1), hi2 = pkrtz(p2, p3);
      f16x4 pk = {lo2[0], lo2[1], hi2[0], hi2[1]};
      *(f16x4*)&psl[l16 * 72 + kt * 16 + 4 * g] = pk;
    }
    cs += __shfl_xor(cs, 16);
    cs += __shfl_xor(cs, 32);
    srun = srun * scl + cs;
#pragma unroll
    for (int ht = 0; ht < 4; ++ht) O[ht] *= scl;
    // make P writes visible to this wave's reads, defeat MFMA hoisting
    asm volatile("s_waitcnt lgkmcnt(0)" ::: "memory");
    __builtin_amdgcn_sched_barrier(0);
    // PV: O^T[h][qr] += v^T[h][k] * P^T[k][qr]
#pragma unroll
    for (int ks2 = 0; ks2 < 2; ++ks2) {
      f16x8 bp = *(const f16x8*)&psl[l16 * 72 + ks2 * 32 + g * 8];
#pragma unroll
      for (int ht = 0; ht < 4; ++ht) {
        f16x8 av = *(const f16x8*)&vT[(ht * 16 + l16) * 264 + kb + ks2 * 32 + g * 8];
        __builtin_amdgcn_s_setprio(1);
        O[ht] = MFMA16(av, bp, O[ht]);
        __builtin_amdgcn_s_setprio(0);
      }
    }
  }

  // ---- output: out[qr][h] = O^T[h][qr] / srun ----
  const float inv = 1.0f / srun;
#pragma unroll
  for (int ht = 0; ht < 4; ++ht) {
    f32x4 r = O[ht] * inv;
    *(f32x4*)&out[((size_t)b * 256 + qr) * 64 + ht * 16 + 4 * g] = r;
  }
}

// ---------------------------------------------------------------------------
extern "C" void kernel_launch(void* const* d_in, const int* in_sizes, int n_in,
                              void* d_out, int out_size, void* d_ws, size_t ws_size,
                              hipStream_t stream) {
  const float* x  = (const float*)d_in[0];
  const float* Wq = (const float*)d_in[1];
  const float* Wk = (const float*)d_in[2];
  const float* Wv = (const float*)d_in[3];

  _Float16* wstg = (_Float16*)d_ws;  // 12*1536*16B = 294912 B

  wprep_kernel<<<72, 256, 0, stream>>>(Wq, Wk, Wv, wstg);
  fused_kernel<<<512, 1024, 0, stream>>>(x, wstg, (float*)d_out);
}